// Round 1
// baseline (822.790 us; speedup 1.0000x reference)
//
#include <hip/hip_runtime.h>

#define NIN 784
#define H0 256
#define H1 128
#define H2 64
#define H3 32
#define NOUT 10
#define BATCH 128
#define TT 500
#define KCH 25   // ceil(784/32)
#define JTILES 16

// d_out offsets (floats)
#define H1_OFF (BATCH * H0 * TT)
#define H2_OFF (H1_OFF + BATCH * H1 * TT)
#define H3_OFF (H2_OFF + BATCH * H2 * TT)
#define OUT_OFF (H3_OFF + BATCH * H3 * TT)
#define RATE_OFF (OUT_OFF + BATCH * NOUT * TT)

typedef __attribute__((ext_vector_type(8))) short short8v;
typedef __attribute__((ext_vector_type(4))) float f32x4;

__device__ __forceinline__ unsigned short f2bf(float f) {
  union { float f; unsigned u; } v; v.f = f;
  unsigned r = v.u + 0x7FFFu + ((v.u >> 16) & 1u);  // RNE
  return (unsigned short)(r >> 16);
}
__device__ __forceinline__ float bf2f(unsigned short b) {
  union { unsigned u; float f; } v; v.u = ((unsigned)b) << 16;
  return v.f;
}
__device__ __forceinline__ float sigm5(float v) {
  return 1.0f / (1.0f + __expf(-5.0f * (v - 1.0f)));
}

// ---------------- kernel P: pack relu(w0) into MFMA A-fragment order ----------
// Wf[(jt*KCH + kc)*64 + lane] = 8 bf16: A[row=jt*16+(lane&15)][k=kc*32+(lane>>4)*8 + e]
__global__ void pack_w0(const float* __restrict__ w0, unsigned short* __restrict__ Wf) {
  const int tile = blockIdx.x;          // jt*KCH + kc
  const int jt = tile / KCH, kc = tile % KCH;
  const int l = threadIdx.x;            // 0..63
  const int j = jt * 16 + (l & 15);
  const int kbase = kc * 32 + (l >> 4) * 8;
  unsigned v[4];
#pragma unroll
  for (int e = 0; e < 4; ++e) {
    const int k0 = kbase + e * 2;
    const float f0 = (k0 < NIN) ? fmaxf(w0[(size_t)k0 * H0 + j], 0.0f) : 0.0f;
    const float f1 = (k0 + 1 < NIN) ? fmaxf(w0[(size_t)(k0 + 1) * H0 + j], 0.0f) : 0.0f;
    v[e] = (unsigned)f2bf(f0) | ((unsigned)f2bf(f1) << 16);
  }
  uint4 o; o.x = v[0]; o.y = v[1]; o.z = v[2]; o.w = v[3];
  reinterpret_cast<uint4*>(Wf)[(size_t)tile * 64 + l] = o;
}

// ---------------- kernel A: cur0[b][t][j] = sum_k relu(w0)[k][j] * X[b][k][t] --
// C(j,t) = Wt(j,k) @ X(k,t); MFMA 16x16x32 bf16, M=j N=t. Block: 256 thr, 4 waves,
// wave w covers j in [w*64, w*64+64), block covers t-tile of 64. grid (8, BATCH).
__global__ __launch_bounds__(256) void gemm0(
    const float* __restrict__ X, const unsigned short* __restrict__ Wf,
    unsigned short* __restrict__ cur0) {
  const int ttile = blockIdx.x;
  const int b = blockIdx.y;
  const int tid = threadIdx.x;
  const int wave = tid >> 6, lane = tid & 63;
  const int t0 = ttile * 64;
  __shared__ unsigned short Xs[64 * 40];  // [t][k] bf16, padded 32->40 (16B-aligned rows)
  f32x4 acc[4][4];
#pragma unroll
  for (int i = 0; i < 4; ++i)
#pragma unroll
    for (int jj = 0; jj < 4; ++jj) acc[i][jj] = (f32x4)0.0f;

  const float* Xb = X + (size_t)b * NIN * TT;
  const int tt = tid & 63;          // staging: one t per thread
  const int kb = (tid >> 6) * 2;    // k-pair base
  const int lrow = lane & 15, lgrp = lane >> 4;

  for (int kc = 0; kc < KCH; ++kc) {
    const int k0 = kc * 32;
    __syncthreads();
    // stage X tile (32k x 64t) transposed into Xs[t][k], fp32->bf16
#pragma unroll
    for (int pp = 0; pp < 4; ++pp) {
      const int kk = kb + pp * 8;
      const int k = k0 + kk;
      const int t = t0 + tt;
      float va = 0.0f, vb = 0.0f;
      if (t < TT) {
        if (k < NIN) va = Xb[(size_t)k * TT + t];
        if (k + 1 < NIN) vb = Xb[(size_t)(k + 1) * TT + t];
      }
      const unsigned pk = (unsigned)f2bf(va) | ((unsigned)f2bf(vb) << 16);
      *reinterpret_cast<unsigned*>(&Xs[tt * 40 + kk]) = pk;
    }
    __syncthreads();

    short8v afr[4], bfr[4];
#pragma unroll
    for (int jf = 0; jf < 4; ++jf) {
      const size_t off = ((size_t)((wave * 4 + jf) * KCH + kc) * 64 + lane) * 8;
      afr[jf] = *reinterpret_cast<const short8v*>(Wf + off);  // global dwordx4, L2-hit
    }
#pragma unroll
    for (int tf = 0; tf < 4; ++tf) {
      const int idx = (tf * 16 + lrow) * 40 + lgrp * 8;
      bfr[tf] = *reinterpret_cast<const short8v*>(Xs + idx);  // ds_read_b128
    }
#pragma unroll
    for (int jf = 0; jf < 4; ++jf)
#pragma unroll
      for (int tf = 0; tf < 4; ++tf)
        acc[jf][tf] = __builtin_amdgcn_mfma_f32_16x16x32_bf16(afr[jf], bfr[tf], acc[jf][tf], 0, 0, 0);
  }

  // store: D row = j = 4*(lane>>4)+reg, col = t = lane&15  (m89-verified layout)
#pragma unroll
  for (int tf = 0; tf < 4; ++tf) {
    const int t = t0 + tf * 16 + lrow;
    if (t >= TT) continue;
    unsigned short* row = cur0 + ((size_t)b * TT + t) * H0;
#pragma unroll
    for (int jf = 0; jf < 4; ++jf) {
      const int j = wave * 64 + jf * 16 + lgrp * 4;
      const f32x4 a = acc[jf][tf];
      const unsigned p0 = (unsigned)f2bf(a[0]) | ((unsigned)f2bf(a[1]) << 16);
      const unsigned p1 = (unsigned)f2bf(a[2]) | ((unsigned)f2bf(a[3]) << 16);
      *reinterpret_cast<unsigned*>(row + j) = p0;
      *reinterpret_cast<unsigned*>(row + j + 2) = p1;
    }
  }
}

// ---------------- kernel B: persistent per-batch LIF stepper -------------------
// 128 blocks x 512 threads. Weights register-resident. Spikes double-buffered in
// LDS (fp32). One barrier per step. All layers within a step are independent
// (layers 1..4 read previous-step spikes).
__global__ __launch_bounds__(512, 2) void snn_steps(
    const unsigned short* __restrict__ cur0,
    const float* __restrict__ w1, const float* __restrict__ w2,
    const float* __restrict__ w3, const float* __restrict__ w4,
    float* __restrict__ out) {
  const int b = blockIdx.x;
  const int tid = threadIdx.x;
  __shared__ __align__(16) float sbuf[2][480];  // s0:0..255, s1:256..383, s2:384..447, s3:448..479

  const int j1 = tid >> 2, q1 = tid & 3;   // layer1: 4 thr/out, 64 MACs each
  const int j2 = tid >> 3, o2 = tid & 7;   // layer2: 8 thr/out, 16 MACs
  const int j3 = tid >> 4, x3 = tid & 15;  // layer3: 16 thr/out, 4 MACs
  const int j4 = tid >> 3, o4 = tid & 7;   // layer4 (tid<80): 8 thr/out, 4 MACs

  // register-resident weights (bank-rotated order matches LDS read order)
  float w1r[64];
#pragma unroll
  for (int kk = 0; kk < 16; ++kk) {
    const int k = (kk + q1 * 4) & 15;
#pragma unroll
    for (int c = 0; c < 4; ++c)
      w1r[kk * 4 + c] = fmaxf(w1[(q1 * 64 + k * 4 + c) * H1 + j1], 0.0f);
  }
  float w2r[16];
#pragma unroll
  for (int kk = 0; kk < 4; ++kk) {
    const int k = (kk + o2) & 3;
#pragma unroll
    for (int c = 0; c < 4; ++c)
      w2r[kk * 4 + c] = fmaxf(w2[(o2 * 16 + k * 4 + c) * H2 + j2], 0.0f);
  }
  float w3r[4];
#pragma unroll
  for (int c = 0; c < 4; ++c) w3r[c] = fmaxf(w3[(x3 * 4 + c) * H3 + j3], 0.0f);
  float w4r[4] = {0.0f, 0.0f, 0.0f, 0.0f};
  if (tid < 80) {
#pragma unroll
    for (int c = 0; c < 4; ++c) w4r[c] = fmaxf(w4[(o4 * 4 + c) * NOUT + j4], 0.0f);
  }

  float v0 = 0.0f, v1 = 0.0f, v2 = 0.0f, v3 = 0.0f, v4 = 0.0f, rate = 0.0f;
  for (int i = tid; i < 960; i += 512) (&sbuf[0][0])[i] = 0.0f;
  __syncthreads();

  const unsigned short* curb = cur0 + (size_t)b * TT * H0;
  float* h0o = out + (size_t)b * H0 * TT;
  float* h1o = out + H1_OFF + (size_t)b * H1 * TT;
  float* h2o = out + H2_OFF + (size_t)b * H2 * TT;
  float* h3o = out + H3_OFF + (size_t)b * H3 * TT;
  float* oo  = out + OUT_OFF + (size_t)b * NOUT * TT;

  int cur = 0;
  for (int t = 0; t < TT; ++t) {
    const float* p = sbuf[cur];
    float* n = sbuf[cur ^ 1];

    float a1 = 0.0f;
    {
      const float4* s0v = reinterpret_cast<const float4*>(p + q1 * 64);
#pragma unroll
      for (int kk = 0; kk < 16; ++kk) {
        const float4 sv = s0v[(kk + q1 * 4) & 15];
        a1 = fmaf(sv.x, w1r[kk * 4 + 0], a1);
        a1 = fmaf(sv.y, w1r[kk * 4 + 1], a1);
        a1 = fmaf(sv.z, w1r[kk * 4 + 2], a1);
        a1 = fmaf(sv.w, w1r[kk * 4 + 3], a1);
      }
    }
    float a2 = 0.0f;
    {
      const float4* s1v = reinterpret_cast<const float4*>(p + 256 + o2 * 16);
#pragma unroll
      for (int kk = 0; kk < 4; ++kk) {
        const float4 sv = s1v[(kk + o2) & 3];
        a2 = fmaf(sv.x, w2r[kk * 4 + 0], a2);
        a2 = fmaf(sv.y, w2r[kk * 4 + 1], a2);
        a2 = fmaf(sv.z, w2r[kk * 4 + 2], a2);
        a2 = fmaf(sv.w, w2r[kk * 4 + 3], a2);
      }
    }
    float a3 = 0.0f;
    {
      const float4 sv = *reinterpret_cast<const float4*>(p + 384 + x3 * 4);
      a3 = fmaf(sv.x, w3r[0], a3);
      a3 = fmaf(sv.y, w3r[1], a3);
      a3 = fmaf(sv.z, w3r[2], a3);
      a3 = fmaf(sv.w, w3r[3], a3);
    }
    float a4 = 0.0f;
    if (tid < 80) {
      const float4 sv = *reinterpret_cast<const float4*>(p + 448 + o4 * 4);
      a4 = fmaf(sv.x, w4r[0], a4);
      a4 = fmaf(sv.y, w4r[1], a4);
      a4 = fmaf(sv.z, w4r[2], a4);
      a4 = fmaf(sv.w, w4r[3], a4);
    }

    a1 += __shfl_xor(a1, 1); a1 += __shfl_xor(a1, 2);
    a2 += __shfl_xor(a2, 1); a2 += __shfl_xor(a2, 2); a2 += __shfl_xor(a2, 4);
    a3 += __shfl_xor(a3, 1); a3 += __shfl_xor(a3, 2); a3 += __shfl_xor(a3, 4); a3 += __shfl_xor(a3, 8);
    if (tid < 80) { a4 += __shfl_xor(a4, 1); a4 += __shfl_xor(a4, 2); a4 += __shfl_xor(a4, 4); }

    if (tid < H0) {  // layer0 LIF, current from precomputed GEMM
      const float c = bf2f(curb[t * H0 + tid]);
      v0 = 0.5f * (v0 + c);
      const float s = sigm5(v0);
      v0 *= (1.0f - s);
      n[tid] = s;
      h0o[tid * TT + t] = s;
    }
    if ((tid & 3) == 0) {
      v1 = 0.5f * (v1 + a1);
      const float s = sigm5(v1);
      v1 *= (1.0f - s);
      n[256 + j1] = s;
      h1o[j1 * TT + t] = s;
    }
    if ((tid & 7) == 0) {
      v2 = 0.5f * (v2 + a2);
      const float s = sigm5(v2);
      v2 *= (1.0f - s);
      n[384 + j2] = s;
      h2o[j2 * TT + t] = s;
    }
    if ((tid & 15) == 0) {
      v3 = 0.5f * (v3 + a3);
      const float s = sigm5(v3);
      v3 *= (1.0f - s);
      n[448 + j3] = s;
      h3o[j3 * TT + t] = s;
    }
    if (tid < 80 && (tid & 7) == 0) {
      v4 = 0.5f * (v4 + a4);
      const float s = sigm5(v4);
      v4 *= (1.0f - s);
      oo[j4 * TT + t] = s;
      rate += s;
    }
    cur ^= 1;
    __syncthreads();
  }
  if (tid < 80 && (tid & 7) == 0)
    out[RATE_OFF + (size_t)b * NOUT + j4] = rate * (1.0f / (float)TT);
}

extern "C" void kernel_launch(void* const* d_in, const int* in_sizes, int n_in,
                              void* d_out, int out_size, void* d_ws, size_t ws_size,
                              hipStream_t stream) {
  const float* X  = (const float*)d_in[0];
  const float* w0 = (const float*)d_in[1];
  const float* w1 = (const float*)d_in[2];
  const float* w2 = (const float*)d_in[3];
  const float* w3 = (const float*)d_in[4];
  const float* w4 = (const float*)d_in[5];
  float* out = (float*)d_out;

  // ws layout: Wf (16*25*64*8 bf16 = 409600 B) | cur0 (128*500*256 bf16 = 32.77 MB)
  unsigned short* Wf = (unsigned short*)d_ws;
  unsigned short* cur0 = Wf + (size_t)JTILES * KCH * 64 * 8;

  pack_w0<<<JTILES * KCH, 64, 0, stream>>>(w0, Wf);
  gemm0<<<dim3(8, BATCH), 256, 0, stream>>>(X, Wf, cur0);
  snn_steps<<<BATCH, 512, 0, stream>>>(cur0, w1, w2, w3, w4, out);
}

// Round 2
// 446.064 us; speedup vs baseline: 1.8446x; 1.8446x over previous
//
#include <hip/hip_runtime.h>

#define NIN 784
#define H0 256
#define H1 128
#define H2 64
#define H3 32
#define NOUT 10
#define BATCH 128
#define TT 500
#define TPAD 512
#define KCH0 25   // ceil(784/32)
#define JTILES 16

// d_out offsets (floats)
#define H1_OFF (BATCH * H0 * TT)
#define H2_OFF (H1_OFF + BATCH * H1 * TT)
#define H3_OFF (H2_OFF + BATCH * H2 * TT)
#define OUT_OFF (H3_OFF + BATCH * H3 * TT)
#define RATE_OFF (OUT_OFF + BATCH * NOUT * TT)

typedef __attribute__((ext_vector_type(8))) short short8v;
typedef __attribute__((ext_vector_type(4))) float f32x4;

__device__ __forceinline__ unsigned short f2bf(float f) {
  union { float f; unsigned u; } v; v.f = f;
  unsigned r = v.u + 0x7FFFu + ((v.u >> 16) & 1u);  // RNE
  return (unsigned short)(r >> 16);
}
__device__ __forceinline__ float bf2f(unsigned short b) {
  union { unsigned u; float f; } v; v.u = ((unsigned)b) << 16;
  return v.f;
}
__device__ __forceinline__ float sigm5(float v) {
  return 1.0f / (1.0f + __expf(-5.0f * (v - 1.0f)));
}

// ---------------- pack relu(w0) into MFMA A-fragment order (verified r1) ------
__global__ void pack_w0(const float* __restrict__ w0, unsigned short* __restrict__ Wf) {
  const int tile = blockIdx.x;          // jt*KCH0 + kc
  const int jt = tile / KCH0, kc = tile % KCH0;
  const int l = threadIdx.x;            // 0..63
  const int j = jt * 16 + (l & 15);
  const int kbase = kc * 32 + (l >> 4) * 8;
  unsigned v[4];
#pragma unroll
  for (int e = 0; e < 4; ++e) {
    const int k0 = kbase + e * 2;
    const float f0 = (k0 < NIN) ? fmaxf(w0[(size_t)k0 * H0 + j], 0.0f) : 0.0f;
    const float f1 = (k0 + 1 < NIN) ? fmaxf(w0[(size_t)(k0 + 1) * H0 + j], 0.0f) : 0.0f;
    v[e] = (unsigned)f2bf(f0) | ((unsigned)f2bf(f1) << 16);
  }
  uint4 o; o.x = v[0]; o.y = v[1]; o.z = v[2]; o.w = v[3];
  reinterpret_cast<uint4*>(Wf)[(size_t)tile * 64 + l] = o;
}

// ---------------- pack relu(w1..w4) into MFMA B-fragment order ----------------
// B frag (16x16x32): lane holds col n = lane&15, k = (lane>>4)*8 + e.
// Tile layout: Bf[base + (rel*64 + lane)*8 + e], rel = nt*KCH + kc.
__global__ void pack_wsmall(const float* __restrict__ w1, const float* __restrict__ w2,
                            const float* __restrict__ w3, const float* __restrict__ w4,
                            unsigned short* __restrict__ Bf) {
  const int tile = blockIdx.x, l = threadIdx.x;
  const float* w; int K, Nw, base, rel;
  if (tile < 64)      { w = w1; K = 256; Nw = 128; base = 0;       rel = tile; }
  else if (tile < 80) { w = w2; K = 128; Nw = 64;  base = 64*512;  rel = tile - 64; }
  else if (tile < 84) { w = w3; K = 64;  Nw = 32;  base = 80*512;  rel = tile - 80; }
  else                { w = w4; K = 32;  Nw = 10;  base = 84*512;  rel = 0; }
  // rel = nt*KCH + kc; recover kc for k-offset, nt for n-offset
  int KCH = (tile < 64) ? 8 : (tile < 80) ? 4 : (tile < 84) ? 2 : 1;
  const int nt = rel / KCH, kc = rel % KCH;
  const int n = nt * 16 + (l & 15);
  const int kb = kc * 32 + (l >> 4) * 8;
  unsigned v[4];
#pragma unroll
  for (int e = 0; e < 4; ++e) {
    const int k0 = kb + e * 2;
    const float f0 = (n < Nw && k0 < K)     ? fmaxf(w[(size_t)k0 * Nw + n], 0.0f) : 0.0f;
    const float f1 = (n < Nw && k0 + 1 < K) ? fmaxf(w[(size_t)(k0 + 1) * Nw + n], 0.0f) : 0.0f;
    v[e] = (unsigned)f2bf(f0) | ((unsigned)f2bf(f1) << 16);
  }
  uint4 o; o.x = v[0]; o.y = v[1]; o.z = v[2]; o.w = v[3];
  *reinterpret_cast<uint4*>(Bf + base + ((size_t)rel * 64 + l) * 8) = o;
}

// ---------------- gemm0: cur0[b][t][j] = sum_k relu(w0)[k][j]*X[b][k][t] (r1) -
__global__ __launch_bounds__(256) void gemm0(
    const float* __restrict__ X, const unsigned short* __restrict__ Wf,
    unsigned short* __restrict__ cur0) {
  const int ttile = blockIdx.x;
  const int b = blockIdx.y;
  const int tid = threadIdx.x;
  const int wave = tid >> 6, lane = tid & 63;
  const int t0 = ttile * 64;
  __shared__ unsigned short Xs[64 * 40];
  f32x4 acc[4][4];
#pragma unroll
  for (int i = 0; i < 4; ++i)
#pragma unroll
    for (int jj = 0; jj < 4; ++jj) acc[i][jj] = (f32x4)0.0f;

  const float* Xb = X + (size_t)b * NIN * TT;
  const int tt = tid & 63;
  const int kb = (tid >> 6) * 2;
  const int lrow = lane & 15, lgrp = lane >> 4;

  for (int kc = 0; kc < KCH0; ++kc) {
    const int k0 = kc * 32;
    __syncthreads();
#pragma unroll
    for (int pp = 0; pp < 4; ++pp) {
      const int kk = kb + pp * 8;
      const int k = k0 + kk;
      const int t = t0 + tt;
      float va = 0.0f, vb = 0.0f;
      if (t < TT) {
        if (k < NIN) va = Xb[(size_t)k * TT + t];
        if (k + 1 < NIN) vb = Xb[(size_t)(k + 1) * TT + t];
      }
      const unsigned pk = (unsigned)f2bf(va) | ((unsigned)f2bf(vb) << 16);
      *reinterpret_cast<unsigned*>(&Xs[tt * 40 + kk]) = pk;
    }
    __syncthreads();

    short8v afr[4], bfr[4];
#pragma unroll
    for (int jf = 0; jf < 4; ++jf) {
      const size_t off = ((size_t)((wave * 4 + jf) * KCH0 + kc) * 64 + lane) * 8;
      afr[jf] = *reinterpret_cast<const short8v*>(Wf + off);
    }
#pragma unroll
    for (int tf = 0; tf < 4; ++tf) {
      const int idx = (tf * 16 + lrow) * 40 + lgrp * 8;
      bfr[tf] = *reinterpret_cast<const short8v*>(Xs + idx);
    }
#pragma unroll
    for (int jf = 0; jf < 4; ++jf)
#pragma unroll
      for (int tf = 0; tf < 4; ++tf)
        acc[jf][tf] = __builtin_amdgcn_mfma_f32_16x16x32_bf16(afr[jf], bfr[tf], acc[jf][tf], 0, 0, 0);
  }

#pragma unroll
  for (int tf = 0; tf < 4; ++tf) {
    const int t = t0 + tf * 16 + lrow;
    if (t >= TT) continue;
    unsigned short* row = cur0 + ((size_t)b * TT + t) * H0;
#pragma unroll
    for (int jf = 0; jf < 4; ++jf) {
      const int j = wave * 64 + jf * 16 + lgrp * 4;
      const f32x4 a = acc[jf][tf];
      const unsigned p0 = (unsigned)f2bf(a[0]) | ((unsigned)f2bf(a[1]) << 16);
      const unsigned p1 = (unsigned)f2bf(a[2]) | ((unsigned)f2bf(a[3]) << 16);
      *reinterpret_cast<unsigned*>(row + j) = p0;
      *reinterpret_cast<unsigned*>(row + j + 2) = p1;
    }
  }
}

// ---------------- gemm_small: C[b][t][n] = sum_k S[b][t][k]*Bfrag -------------
// A frag directly from S rows (bf16 [b][TPAD][K]); entire A tile (16 rows x K)
// held in registers. grid (8, B), 256 thr = 4 waves, wave handles 16 t-rows.
template<int K, int NT, int KCH, int NA>
__global__ __launch_bounds__(256) void gemm_small(
    const unsigned short* __restrict__ S, const unsigned short* __restrict__ Bf,
    float* __restrict__ C) {
  const int b = blockIdx.y;
  const int wave = threadIdx.x >> 6, lane = threadIdx.x & 63;
  const int t0 = blockIdx.x * 64 + wave * 16;
  const unsigned short* Sb = S + ((size_t)b * TPAD + t0 + (lane & 15)) * K + (lane >> 4) * 8;
  short8v afr[KCH];
#pragma unroll
  for (int kc = 0; kc < KCH; ++kc) afr[kc] = *reinterpret_cast<const short8v*>(Sb + kc * 32);
  float* Cb = C + ((size_t)b * TPAD + t0 + (lane >> 4) * 4) * NA + (lane & 15);
#pragma unroll
  for (int nt = 0; nt < NT; ++nt) {
    f32x4 acc = (f32x4)0.0f;
#pragma unroll
    for (int kc = 0; kc < KCH; ++kc) {
      const short8v bfr = *reinterpret_cast<const short8v*>(Bf + ((size_t)(nt * KCH + kc) * 64 + lane) * 8);
      acc = __builtin_amdgcn_mfma_f32_16x16x32_bf16(afr[kc], bfr, acc, 0, 0, 0);
    }
#pragma unroll
    for (int r = 0; r < 4; ++r) Cb[(size_t)r * NA + nt * 16] = acc[r];
  }
}

// ---------------- scan0: per-neuron LIF over t; cur bf16 [b][TT][256] ---------
__global__ __launch_bounds__(64) void scan0(
    const unsigned short* __restrict__ cur0, unsigned short* __restrict__ s0,
    float* __restrict__ h0) {
  const int b = blockIdx.y, jg = blockIdx.x, l = threadIdx.x;
  const int j = jg * 64 + l;
  const unsigned short* cp = cur0 + (size_t)b * TT * H0 + j;
  unsigned short* sp = s0 + (size_t)b * TPAD * H0 + j;
  float* hp = h0 + ((size_t)b * H0 + j) * TT;
  sp[0] = 0;
  float v = 0.0f;
  int t = 0;
  for (; t + 8 <= TT; t += 8) {
    float c[8];
#pragma unroll
    for (int u = 0; u < 8; ++u) c[u] = bf2f(cp[(size_t)(t + u) * H0]);
    float hb[8];
#pragma unroll
    for (int u = 0; u < 8; ++u) {
      v = 0.5f * (v + c[u]);
      const float s = sigm5(v);
      v *= (1.0f - s);
      hb[u] = s;
      sp[(size_t)(t + u + 1) * H0] = f2bf(s);
    }
    *reinterpret_cast<float4*>(hp + t) = make_float4(hb[0], hb[1], hb[2], hb[3]);
    *reinterpret_cast<float4*>(hp + t + 4) = make_float4(hb[4], hb[5], hb[6], hb[7]);
  }
  {  // tail 4
    float c[4];
#pragma unroll
    for (int u = 0; u < 4; ++u) c[u] = bf2f(cp[(size_t)(t + u) * H0]);
    float hb[4];
#pragma unroll
    for (int u = 0; u < 4; ++u) {
      v = 0.5f * (v + c[u]);
      const float s = sigm5(v);
      v *= (1.0f - s);
      hb[u] = s;
      sp[(size_t)(t + u + 1) * H0] = f2bf(s);
    }
    *reinterpret_cast<float4*>(hp + t) = make_float4(hb[0], hb[1], hb[2], hb[3]);
  }
}

// ---------------- scan_mid: cur fp32 [b][TPAD][H] -> h out + sbuf -------------
template<int H>
__global__ __launch_bounds__(64) void scan_mid(
    const float* __restrict__ cur, unsigned short* __restrict__ sbuf,
    float* __restrict__ h) {
  const int b = blockIdx.y, jg = blockIdx.x, l = threadIdx.x;
  if (H < 64 && l >= H) return;
  const int j = jg * 64 + l;
  const float* cp = cur + (size_t)b * TPAD * H + j;
  unsigned short* sp = sbuf + (size_t)b * TPAD * H + j;
  float* hp = h + ((size_t)b * H + j) * TT;
  sp[0] = 0;
  float v = 0.0f;
  int t = 0;
  for (; t + 8 <= TT; t += 8) {
    float c[8];
#pragma unroll
    for (int u = 0; u < 8; ++u) c[u] = cp[(size_t)(t + u) * H];
    float hb[8];
#pragma unroll
    for (int u = 0; u < 8; ++u) {
      v = 0.5f * (v + c[u]);
      const float s = sigm5(v);
      v *= (1.0f - s);
      hb[u] = s;
      sp[(size_t)(t + u + 1) * H] = f2bf(s);
    }
    *reinterpret_cast<float4*>(hp + t) = make_float4(hb[0], hb[1], hb[2], hb[3]);
    *reinterpret_cast<float4*>(hp + t + 4) = make_float4(hb[4], hb[5], hb[6], hb[7]);
  }
  {
    float c[4];
#pragma unroll
    for (int u = 0; u < 4; ++u) c[u] = cp[(size_t)(t + u) * H];
    float hb[4];
#pragma unroll
    for (int u = 0; u < 4; ++u) {
      v = 0.5f * (v + c[u]);
      const float s = sigm5(v);
      v *= (1.0f - s);
      hb[u] = s;
      sp[(size_t)(t + u + 1) * H] = f2bf(s);
    }
    *reinterpret_cast<float4*>(hp + t) = make_float4(hb[0], hb[1], hb[2], hb[3]);
  }
}

// ---------------- scan_out: cur4 fp32 [b][TPAD][16] -> output spikes + rates ---
__global__ __launch_bounds__(64) void scan_out(
    const float* __restrict__ cur, float* __restrict__ oo, float* __restrict__ rates) {
  const int b = blockIdx.y, l = threadIdx.x;
  if (l >= NOUT) return;
  const float* cp = cur + (size_t)b * TPAD * 16 + l;
  float* hp = oo + ((size_t)b * NOUT + l) * TT;
  float v = 0.0f, rate = 0.0f;
  int t = 0;
  for (; t + 8 <= TT; t += 8) {
    float c[8];
#pragma unroll
    for (int u = 0; u < 8; ++u) c[u] = cp[(size_t)(t + u) * 16];
    float hb[8];
#pragma unroll
    for (int u = 0; u < 8; ++u) {
      v = 0.5f * (v + c[u]);
      const float s = sigm5(v);
      v *= (1.0f - s);
      hb[u] = s;
      rate += s;
    }
    *reinterpret_cast<float4*>(hp + t) = make_float4(hb[0], hb[1], hb[2], hb[3]);
    *reinterpret_cast<float4*>(hp + t + 4) = make_float4(hb[4], hb[5], hb[6], hb[7]);
  }
  {
    float c[4];
#pragma unroll
    for (int u = 0; u < 4; ++u) c[u] = cp[(size_t)(t + u) * 16];
    float hb[4];
#pragma unroll
    for (int u = 0; u < 4; ++u) {
      v = 0.5f * (v + c[u]);
      const float s = sigm5(v);
      v *= (1.0f - s);
      hb[u] = s;
      rate += s;
    }
    *reinterpret_cast<float4*>(hp + t) = make_float4(hb[0], hb[1], hb[2], hb[3]);
  }
  rates[(size_t)b * NOUT + l] = rate * (1.0f / (float)TT);
}

extern "C" void kernel_launch(void* const* d_in, const int* in_sizes, int n_in,
                              void* d_out, int out_size, void* d_ws, size_t ws_size,
                              hipStream_t stream) {
  const float* X  = (const float*)d_in[0];
  const float* w0 = (const float*)d_in[1];
  const float* w1 = (const float*)d_in[2];
  const float* w2 = (const float*)d_in[3];
  const float* w3 = (const float*)d_in[4];
  const float* w4 = (const float*)d_in[5];
  float* out = (float*)d_out;

  // ws: slotA (32MB) | slotB (32MB) | Wf0 (400KB) | Bf2 (85KB). Ping-pong slots.
  uint8_t* ws = (uint8_t*)d_ws;
  const size_t SLOT = 33554432;  // 128*512*256*2 == 128*512*128*4
  uint8_t* slotA = ws;
  uint8_t* slotB = ws + SLOT;
  unsigned short* Wf0 = (unsigned short*)(ws + 2 * SLOT);
  unsigned short* Bf2 = Wf0 + (size_t)JTILES * KCH0 * 64 * 8;  // +204800 shorts

  unsigned short* cur0 = (unsigned short*)slotA;  // [b][TT][256]
  unsigned short* s0   = (unsigned short*)slotB;  // [b][TPAD][256]
  float*          cur1 = (float*)slotA;           // [b][TPAD][128]
  unsigned short* s1   = (unsigned short*)slotB;  // [b][TPAD][128]
  float*          cur2 = (float*)slotA;           // [b][TPAD][64]
  unsigned short* s2   = (unsigned short*)slotB;  // [b][TPAD][64]
  float*          cur3 = (float*)slotA;           // [b][TPAD][32]
  unsigned short* s3   = (unsigned short*)slotB;  // [b][TPAD][32]
  float*          cur4 = (float*)slotA;           // [b][TPAD][16]

  pack_w0<<<JTILES * KCH0, 64, 0, stream>>>(w0, Wf0);
  pack_wsmall<<<85, 64, 0, stream>>>(w1, w2, w3, w4, Bf2);

  gemm0<<<dim3(8, BATCH), 256, 0, stream>>>(X, Wf0, cur0);
  scan0<<<dim3(4, BATCH), 64, 0, stream>>>(cur0, s0, out);

  gemm_small<256, 8, 8, 128><<<dim3(8, BATCH), 256, 0, stream>>>(s0, Bf2, cur1);
  scan_mid<128><<<dim3(2, BATCH), 64, 0, stream>>>(cur1, s1, out + H1_OFF);

  gemm_small<128, 4, 4, 64><<<dim3(8, BATCH), 256, 0, stream>>>(s1, Bf2 + 64 * 512, cur2);
  scan_mid<64><<<dim3(1, BATCH), 64, 0, stream>>>(cur2, s2, out + H2_OFF);

  gemm_small<64, 2, 2, 32><<<dim3(8, BATCH), 256, 0, stream>>>(s2, Bf2 + 80 * 512, cur3);
  scan_mid<32><<<dim3(1, BATCH), 64, 0, stream>>>(cur3, s3, out + H3_OFF);

  gemm_small<32, 1, 1, 16><<<dim3(8, BATCH), 256, 0, stream>>>(s3, Bf2 + 84 * 512, cur4);
  scan_out<<<dim3(1, BATCH), 64, 0, stream>>>(cur4, out + OUT_OFF, out + RATE_OFF);
}

// Round 3
// 295.098 us; speedup vs baseline: 2.7882x; 1.5116x over previous
//
#include <hip/hip_runtime.h>

#define NIN 784
#define H0 256
#define H1 128
#define H2 64
#define H3 32
#define NOUT 10
#define BATCH 128
#define TT 500
#define TPAD 512
#define KCH0 25   // ceil(784/32)
#define JTILES 16

// d_out offsets (floats)
#define H1_OFF (BATCH * H0 * TT)
#define H2_OFF (H1_OFF + BATCH * H1 * TT)
#define H3_OFF (H2_OFF + BATCH * H2 * TT)
#define OUT_OFF (H3_OFF + BATCH * H3 * TT)
#define RATE_OFF (OUT_OFF + BATCH * NOUT * TT)

typedef __attribute__((ext_vector_type(8))) short short8v;
typedef __attribute__((ext_vector_type(4))) float f32x4;

__device__ __forceinline__ unsigned short f2bf(float f) {
  union { float f; unsigned u; } v; v.f = f;
  unsigned r = v.u + 0x7FFFu + ((v.u >> 16) & 1u);  // RNE
  return (unsigned short)(r >> 16);
}
__device__ __forceinline__ float bf2f(unsigned short b) {
  union { unsigned u; float f; } v; v.u = ((unsigned)b) << 16;
  return v.f;
}
__device__ __forceinline__ float sigm5(float v) {
  return 1.0f / (1.0f + __expf(-5.0f * (v - 1.0f)));
}

// ---------------- pack_all: w0 -> A-frags (tiles 0..399), w1..w4 -> B-frags ---
__global__ void pack_all(const float* __restrict__ w0, const float* __restrict__ w1,
                         const float* __restrict__ w2, const float* __restrict__ w3,
                         const float* __restrict__ w4, unsigned short* __restrict__ Wf,
                         unsigned short* __restrict__ Bf) {
  const int bid = blockIdx.x, l = threadIdx.x;
  if (bid < JTILES * KCH0) {
    const int jt = bid / KCH0, kc = bid % KCH0;
    const int j = jt * 16 + (l & 15);
    const int kbase = kc * 32 + (l >> 4) * 8;
    unsigned v[4];
#pragma unroll
    for (int e = 0; e < 4; ++e) {
      const int k0 = kbase + e * 2;
      const float f0 = (k0 < NIN) ? fmaxf(w0[(size_t)k0 * H0 + j], 0.0f) : 0.0f;
      const float f1 = (k0 + 1 < NIN) ? fmaxf(w0[(size_t)(k0 + 1) * H0 + j], 0.0f) : 0.0f;
      v[e] = (unsigned)f2bf(f0) | ((unsigned)f2bf(f1) << 16);
    }
    uint4 o; o.x = v[0]; o.y = v[1]; o.z = v[2]; o.w = v[3];
    reinterpret_cast<uint4*>(Wf)[(size_t)bid * 64 + l] = o;
    return;
  }
  const int tile = bid - JTILES * KCH0;
  const float* w; int K, Nw, base, rel, KCH;
  if (tile < 64)      { w = w1; K = 256; Nw = 128; base = 0;        rel = tile;      KCH = 8; }
  else if (tile < 80) { w = w2; K = 128; Nw = 64;  base = 64 * 512; rel = tile - 64; KCH = 4; }
  else if (tile < 84) { w = w3; K = 64;  Nw = 32;  base = 80 * 512; rel = tile - 80; KCH = 2; }
  else                { w = w4; K = 32;  Nw = 10;  base = 84 * 512; rel = 0;         KCH = 1; }
  const int nt = rel / KCH, kc = rel % KCH;
  const int n = nt * 16 + (l & 15);
  const int kb = kc * 32 + (l >> 4) * 8;
  unsigned v[4];
#pragma unroll
  for (int e = 0; e < 4; ++e) {
    const int k0 = kb + e * 2;
    const float f0 = (n < Nw && k0 < K)     ? fmaxf(w[(size_t)k0 * Nw + n], 0.0f) : 0.0f;
    const float f1 = (n < Nw && k0 + 1 < K) ? fmaxf(w[(size_t)(k0 + 1) * Nw + n], 0.0f) : 0.0f;
    v[e] = (unsigned)f2bf(f0) | ((unsigned)f2bf(f1) << 16);
  }
  uint4 o; o.x = v[0]; o.y = v[1]; o.z = v[2]; o.w = v[3];
  *reinterpret_cast<uint4*>(Bf + base + ((size_t)rel * 64 + l) * 8) = o;
}

// ---------------- gemm0 (pipelined): cur0[b][t][j] = sum_k relu(w0)[k][j]*X[b][k][t]
// Double-buffered LDS, register prefetch of next X chunk issued after the
// barrier (so the __syncthreads vmcnt-drain hits one chunk later).
__global__ __launch_bounds__(256, 4) void gemm0(
    const float* __restrict__ X, const unsigned short* __restrict__ Wf,
    unsigned short* __restrict__ cur0) {
  const int ttile = blockIdx.x;
  const int b = blockIdx.y;
  const int tid = threadIdx.x;
  const int wave = tid >> 6, lane = tid & 63;
  const int t0 = ttile * 64;
  __shared__ unsigned short Xs[2][64 * 40];
  f32x4 acc[4][4];
#pragma unroll
  for (int i = 0; i < 4; ++i)
#pragma unroll
    for (int jj = 0; jj < 4; ++jj) acc[i][jj] = (f32x4)0.0f;

  const float* Xb = X + (size_t)b * NIN * TT;
  const int tt = tid & 63;
  const int kb = wave * 2;
  const int lrow = lane & 15, lgrp = lane >> 4;
  const int tgl = t0 + tt;
  const bool tin = tgl < TT;

  float r[8];
  // prologue: load chunk 0 (k <= 31, always in range)
#pragma unroll
  for (int pp = 0; pp < 4; ++pp) {
    const int k = kb + pp * 8;
    r[pp * 2]     = tin ? Xb[(size_t)k * TT + tgl] : 0.0f;
    r[pp * 2 + 1] = tin ? Xb[(size_t)(k + 1) * TT + tgl] : 0.0f;
  }

  for (int kc = 0; kc < KCH0; ++kc) {
    unsigned short* xbuf = Xs[kc & 1];
    // ds_write current chunk (consumes r)
#pragma unroll
    for (int pp = 0; pp < 4; ++pp) {
      const unsigned pk = (unsigned)f2bf(r[pp * 2]) | ((unsigned)f2bf(r[pp * 2 + 1]) << 16);
      *reinterpret_cast<unsigned*>(&xbuf[tt * 40 + kb + pp * 8]) = pk;
    }
    __syncthreads();
    // prefetch next chunk into regs (in flight across MFMA, drained at next barrier)
    if (kc + 1 < KCH0) {
      const int k0 = (kc + 1) * 32;
#pragma unroll
      for (int pp = 0; pp < 4; ++pp) {
        const int k = k0 + kb + pp * 8;
        r[pp * 2]     = (tin && k < NIN)     ? Xb[(size_t)k * TT + tgl] : 0.0f;
        r[pp * 2 + 1] = (tin && k + 1 < NIN) ? Xb[(size_t)(k + 1) * TT + tgl] : 0.0f;
      }
    }
    short8v afr[4], bfr[4];
#pragma unroll
    for (int jf = 0; jf < 4; ++jf) {
      const size_t off = ((size_t)((wave * 4 + jf) * KCH0 + kc) * 64 + lane) * 8;
      afr[jf] = *reinterpret_cast<const short8v*>(Wf + off);
    }
#pragma unroll
    for (int tf = 0; tf < 4; ++tf)
      bfr[tf] = *reinterpret_cast<const short8v*>(&xbuf[(tf * 16 + lrow) * 40 + lgrp * 8]);
#pragma unroll
    for (int jf = 0; jf < 4; ++jf)
#pragma unroll
      for (int tf = 0; tf < 4; ++tf)
        acc[jf][tf] = __builtin_amdgcn_mfma_f32_16x16x32_bf16(afr[jf], bfr[tf], acc[jf][tf], 0, 0, 0);
  }

#pragma unroll
  for (int tf = 0; tf < 4; ++tf) {
    const int t = t0 + tf * 16 + lrow;
    if (t >= TT) continue;
    unsigned short* row = cur0 + ((size_t)b * TT + t) * H0;
#pragma unroll
    for (int jf = 0; jf < 4; ++jf) {
      const int j = wave * 64 + jf * 16 + lgrp * 4;
      const f32x4 a = acc[jf][tf];
      const unsigned p0 = (unsigned)f2bf(a[0]) | ((unsigned)f2bf(a[1]) << 16);
      const unsigned p1 = (unsigned)f2bf(a[2]) | ((unsigned)f2bf(a[3]) << 16);
      *reinterpret_cast<unsigned*>(row + j) = p0;
      *reinterpret_cast<unsigned*>(row + j + 2) = p1;
    }
  }
}

// ---------------- gemm_small: C[b][t][n] = sum_k S[b][t][k]*Bfrag -------------
template<int K, int NT, int KCH, int NA>
__global__ __launch_bounds__(256) void gemm_small(
    const unsigned short* __restrict__ S, const unsigned short* __restrict__ Bf,
    float* __restrict__ C) {
  const int b = blockIdx.y;
  const int wave = threadIdx.x >> 6, lane = threadIdx.x & 63;
  const int t0 = blockIdx.x * 64 + wave * 16;
  const unsigned short* Sb = S + ((size_t)b * TPAD + t0 + (lane & 15)) * K + (lane >> 4) * 8;
  short8v afr[KCH];
#pragma unroll
  for (int kc = 0; kc < KCH; ++kc) afr[kc] = *reinterpret_cast<const short8v*>(Sb + kc * 32);
  float* Cb = C + ((size_t)b * TPAD + t0 + (lane >> 4) * 4) * NA + (lane & 15);
#pragma unroll
  for (int nt = 0; nt < NT; ++nt) {
    f32x4 acc = (f32x4)0.0f;
#pragma unroll
    for (int kc = 0; kc < KCH; ++kc) {
      const short8v bfr = *reinterpret_cast<const short8v*>(Bf + ((size_t)(nt * KCH + kc) * 64 + lane) * 8);
      acc = __builtin_amdgcn_mfma_f32_16x16x32_bf16(afr[kc], bfr, acc, 0, 0, 0);
    }
#pragma unroll
    for (int r = 0; r < 4; ++r) Cb[(size_t)r * NA + nt * 16] = acc[r];
  }
}

// 16-step LIF block: serial chain on v, spike writes (strided bf16) + line-buffered h
#define STEP16(C, TB, Hdim)                                                         \
  do {                                                                              \
    float hb[16];                                                                   \
    _Pragma("unroll")                                                               \
    for (int u = 0; u < 16; ++u) {                                                  \
      v = 0.5f * (v + (C)[u]);                                                      \
      const float s = sigm5(v);                                                     \
      v *= (1.0f - s);                                                              \
      hb[u] = s;                                                                    \
      sp[(size_t)((TB) + u + 1) * (Hdim)] = f2bf(s);                                \
    }                                                                               \
    _Pragma("unroll")                                                               \
    for (int q = 0; q < 4; ++q)                                                     \
      *reinterpret_cast<float4*>(hp + (TB) + q * 4) =                               \
          make_float4(hb[q * 4], hb[q * 4 + 1], hb[q * 4 + 2], hb[q * 4 + 3]);      \
  } while (0)

// ---------------- scan0: per-neuron LIF; cur bf16 [b][TT][256] ----------------
__global__ __launch_bounds__(64) void scan0(
    const unsigned short* __restrict__ cur0, unsigned short* __restrict__ s0,
    float* __restrict__ h0) {
  const int b = blockIdx.y, jg = blockIdx.x, l = threadIdx.x;
  const int j = jg * 64 + l;
  const unsigned short* cp = cur0 + (size_t)b * TT * H0 + j;
  unsigned short* sp = s0 + (size_t)b * TPAD * H0 + j;
  float* hp = h0 + ((size_t)b * H0 + j) * TT;
  sp[0] = 0;
  float v = 0.0f;
  float c0[16], c1[16];
#define LOADC0(DST, TB)                                                   \
  _Pragma("unroll") for (int u = 0; u < 16; ++u) (DST)[u] = bf2f(cp[(size_t)((TB) + u) * H0]);
  LOADC0(c0, 0);
  for (int i = 0; i < 15; ++i) {
    const int tb = i * 32;
    LOADC0(c1, tb + 16);
    STEP16(c0, tb, H0);
    LOADC0(c0, tb + 32);
    STEP16(c1, tb + 16, H0);
  }
  STEP16(c0, 480, H0);
  {  // tail t=496..499
    float c[4], hb[4];
#pragma unroll
    for (int u = 0; u < 4; ++u) c[u] = bf2f(cp[(size_t)(496 + u) * H0]);
#pragma unroll
    for (int u = 0; u < 4; ++u) {
      v = 0.5f * (v + c[u]);
      const float s = sigm5(v);
      v *= (1.0f - s);
      hb[u] = s;
      sp[(size_t)(496 + u + 1) * H0] = f2bf(s);
    }
    *reinterpret_cast<float4*>(hp + 496) = make_float4(hb[0], hb[1], hb[2], hb[3]);
  }
#undef LOADC0
}

// ---------------- scan_mid: cur fp32 [b][TPAD][H] -> h out + sbuf -------------
template<int H>
__global__ __launch_bounds__(64) void scan_mid(
    const float* __restrict__ cur, unsigned short* __restrict__ sbuf,
    float* __restrict__ h) {
  const int b = blockIdx.y, jg = blockIdx.x, l = threadIdx.x;
  if (H < 64 && l >= H) return;
  const int j = jg * 64 + l;
  const float* cp = cur + (size_t)b * TPAD * H + j;
  unsigned short* sp = sbuf + (size_t)b * TPAD * H + j;
  float* hp = h + ((size_t)b * H + j) * TT;
  sp[0] = 0;
  float v = 0.0f;
  float c0[16], c1[16];
#define LOADCM(DST, TB)                                                   \
  _Pragma("unroll") for (int u = 0; u < 16; ++u) (DST)[u] = cp[(size_t)((TB) + u) * H];
  LOADCM(c0, 0);
  for (int i = 0; i < 15; ++i) {
    const int tb = i * 32;
    LOADCM(c1, tb + 16);
    STEP16(c0, tb, H);
    LOADCM(c0, tb + 32);
    STEP16(c1, tb + 16, H);
  }
  STEP16(c0, 480, H);
  {
    float c[4], hb[4];
#pragma unroll
    for (int u = 0; u < 4; ++u) c[u] = cp[(size_t)(496 + u) * H];
#pragma unroll
    for (int u = 0; u < 4; ++u) {
      v = 0.5f * (v + c[u]);
      const float s = sigm5(v);
      v *= (1.0f - s);
      hb[u] = s;
      sp[(size_t)(496 + u + 1) * H] = f2bf(s);
    }
    *reinterpret_cast<float4*>(hp + 496) = make_float4(hb[0], hb[1], hb[2], hb[3]);
  }
#undef LOADCM
}

// ---------------- scan_out: cur4 fp32 [b][TPAD][16] -> output spikes + rates --
__global__ __launch_bounds__(64) void scan_out(
    const float* __restrict__ cur, float* __restrict__ oo, float* __restrict__ rates) {
  const int b = blockIdx.y, l = threadIdx.x;
  if (l >= NOUT) return;
  const float* cp = cur + (size_t)b * TPAD * 16 + l;
  float* hp = oo + ((size_t)b * NOUT + l) * TT;
  float v = 0.0f, rate = 0.0f;
  float c0[16], c1[16];
#define LOADCO(DST, TB)                                                   \
  _Pragma("unroll") for (int u = 0; u < 16; ++u) (DST)[u] = cp[(size_t)((TB) + u) * 16];
#define OSTEP16(C, TB)                                                              \
  do {                                                                              \
    float hb[16];                                                                   \
    _Pragma("unroll")                                                               \
    for (int u = 0; u < 16; ++u) {                                                  \
      v = 0.5f * (v + (C)[u]);                                                      \
      const float s = sigm5(v);                                                     \
      v *= (1.0f - s);                                                              \
      hb[u] = s;                                                                    \
      rate += s;                                                                    \
    }                                                                               \
    _Pragma("unroll")                                                               \
    for (int q = 0; q < 4; ++q)                                                     \
      *reinterpret_cast<float4*>(hp + (TB) + q * 4) =                               \
          make_float4(hb[q * 4], hb[q * 4 + 1], hb[q * 4 + 2], hb[q * 4 + 3]);      \
  } while (0)
  LOADCO(c0, 0);
  for (int i = 0; i < 15; ++i) {
    const int tb = i * 32;
    LOADCO(c1, tb + 16);
    OSTEP16(c0, tb);
    LOADCO(c0, tb + 32);
    OSTEP16(c1, tb + 16);
  }
  OSTEP16(c0, 480);
  {
    float c[4], hb[4];
#pragma unroll
    for (int u = 0; u < 4; ++u) c[u] = cp[(size_t)(496 + u) * 16];
#pragma unroll
    for (int u = 0; u < 4; ++u) {
      v = 0.5f * (v + c[u]);
      const float s = sigm5(v);
      v *= (1.0f - s);
      hb[u] = s;
      rate += s;
    }
    *reinterpret_cast<float4*>(hp + 496) = make_float4(hb[0], hb[1], hb[2], hb[3]);
  }
  rates[(size_t)b * NOUT + l] = rate * (1.0f / (float)TT);
#undef LOADCO
#undef OSTEP16
}

extern "C" void kernel_launch(void* const* d_in, const int* in_sizes, int n_in,
                              void* d_out, int out_size, void* d_ws, size_t ws_size,
                              hipStream_t stream) {
  const float* X  = (const float*)d_in[0];
  const float* w0 = (const float*)d_in[1];
  const float* w1 = (const float*)d_in[2];
  const float* w2 = (const float*)d_in[3];
  const float* w3 = (const float*)d_in[4];
  const float* w4 = (const float*)d_in[5];
  float* out = (float*)d_out;

  uint8_t* ws = (uint8_t*)d_ws;
  const size_t SLOT = 33554432;
  uint8_t* slotA = ws;
  uint8_t* slotB = ws + SLOT;
  unsigned short* Wf0 = (unsigned short*)(ws + 2 * SLOT);
  unsigned short* Bf2 = Wf0 + (size_t)JTILES * KCH0 * 64 * 8;

  unsigned short* cur0 = (unsigned short*)slotA;
  unsigned short* s0   = (unsigned short*)slotB;
  float*          cur1 = (float*)slotA;
  unsigned short* s1   = (unsigned short*)slotB;
  float*          cur2 = (float*)slotA;
  unsigned short* s2   = (unsigned short*)slotB;
  float*          cur3 = (float*)slotA;
  unsigned short* s3   = (unsigned short*)slotB;
  float*          cur4 = (float*)slotA;

  pack_all<<<JTILES * KCH0 + 85, 64, 0, stream>>>(w0, w1, w2, w3, w4, Wf0, Bf2);

  gemm0<<<dim3(8, BATCH), 256, 0, stream>>>(X, Wf0, cur0);
  scan0<<<dim3(4, BATCH), 64, 0, stream>>>(cur0, s0, out);

  gemm_small<256, 8, 8, 128><<<dim3(8, BATCH), 256, 0, stream>>>(s0, Bf2, cur1);
  scan_mid<128><<<dim3(2, BATCH), 64, 0, stream>>>(cur1, s1, out + H1_OFF);

  gemm_small<128, 4, 4, 64><<<dim3(8, BATCH), 256, 0, stream>>>(s1, Bf2 + 64 * 512, cur2);
  scan_mid<64><<<dim3(1, BATCH), 64, 0, stream>>>(cur2, s2, out + H2_OFF);

  gemm_small<64, 2, 2, 32><<<dim3(8, BATCH), 256, 0, stream>>>(s2, Bf2 + 80 * 512, cur3);
  scan_mid<32><<<dim3(1, BATCH), 64, 0, stream>>>(cur3, s3, out + H3_OFF);

  gemm_small<32, 1, 1, 16><<<dim3(8, BATCH), 256, 0, stream>>>(s3, Bf2 + 84 * 512, cur4);
  scan_out<<<dim3(1, BATCH), 64, 0, stream>>>(cur4, out + OUT_OFF, out + RATE_OFF);
}

// Round 4
// 255.164 us; speedup vs baseline: 3.2246x; 1.1565x over previous
//
#include <hip/hip_runtime.h>

#define NIN 784
#define H0 256
#define H1 128
#define H2 64
#define H3 32
#define NOUT 10
#define BATCH 128
#define TT 500
#define KCH0 25
#define JTILES 16

// LDS pads: spike rows (bf16) stride ≡4 mod 32 banks; cur rows (fp32) ≡1 mod 32
#define SW0 264
#define SW1 136
#define SW2 72
#define SW3 40
#define CW1 129
#define CW2 65
#define CW3 33
#define CW4 17

// d_out offsets (floats)
#define H1_OFF (BATCH * H0 * TT)
#define H2_OFF (H1_OFF + BATCH * H1 * TT)
#define H3_OFF (H2_OFF + BATCH * H2 * TT)
#define OUT_OFF (H3_OFF + BATCH * H3 * TT)
#define RATE_OFF (OUT_OFF + BATCH * NOUT * TT)

typedef __attribute__((ext_vector_type(8))) short short8v;
typedef __attribute__((ext_vector_type(4))) float f32x4;

__device__ __forceinline__ unsigned short f2bf(float f) {
  union { float f; unsigned u; } v; v.f = f;
  unsigned r = v.u + 0x7FFFu + ((v.u >> 16) & 1u);  // RNE
  return (unsigned short)(r >> 16);
}
__device__ __forceinline__ float bf2f(unsigned short b) {
  union { unsigned u; float f; } v; v.u = ((unsigned)b) << 16;
  return v.f;
}
__device__ __forceinline__ float sigm5(float v) {
  return 1.0f / (1.0f + __expf(-5.0f * (v - 1.0f)));
}

// ---------------- pack_all: w0 -> A-frags, w1..w4 -> B-frags (verified) -------
__global__ void pack_all(const float* __restrict__ w0, const float* __restrict__ w1,
                         const float* __restrict__ w2, const float* __restrict__ w3,
                         const float* __restrict__ w4, unsigned short* __restrict__ Wf,
                         unsigned short* __restrict__ Bf) {
  const int bid = blockIdx.x, l = threadIdx.x;
  if (bid < JTILES * KCH0) {
    const int jt = bid / KCH0, kc = bid % KCH0;
    const int j = jt * 16 + (l & 15);
    const int kbase = kc * 32 + (l >> 4) * 8;
    unsigned v[4];
#pragma unroll
    for (int e = 0; e < 4; ++e) {
      const int k0 = kbase + e * 2;
      const float f0 = (k0 < NIN) ? fmaxf(w0[(size_t)k0 * H0 + j], 0.0f) : 0.0f;
      const float f1 = (k0 + 1 < NIN) ? fmaxf(w0[(size_t)(k0 + 1) * H0 + j], 0.0f) : 0.0f;
      v[e] = (unsigned)f2bf(f0) | ((unsigned)f2bf(f1) << 16);
    }
    uint4 o; o.x = v[0]; o.y = v[1]; o.z = v[2]; o.w = v[3];
    reinterpret_cast<uint4*>(Wf)[(size_t)bid * 64 + l] = o;
    return;
  }
  const int tile = bid - JTILES * KCH0;
  const float* w; int K, Nw, base, rel, KCH;
  if (tile < 64)      { w = w1; K = 256; Nw = 128; base = 0;        rel = tile;      KCH = 8; }
  else if (tile < 80) { w = w2; K = 128; Nw = 64;  base = 64 * 512; rel = tile - 64; KCH = 4; }
  else if (tile < 84) { w = w3; K = 64;  Nw = 32;  base = 80 * 512; rel = tile - 80; KCH = 2; }
  else                { w = w4; K = 32;  Nw = 10;  base = 84 * 512; rel = 0;         KCH = 1; }
  const int nt = rel / KCH, kc = rel % KCH;
  const int n = nt * 16 + (l & 15);
  const int kb = kc * 32 + (l >> 4) * 8;
  unsigned v[4];
#pragma unroll
  for (int e = 0; e < 4; ++e) {
    const int k0 = kb + e * 2;
    const float f0 = (n < Nw && k0 < K)     ? fmaxf(w[(size_t)k0 * Nw + n], 0.0f) : 0.0f;
    const float f1 = (n < Nw && k0 + 1 < K) ? fmaxf(w[(size_t)(k0 + 1) * Nw + n], 0.0f) : 0.0f;
    v[e] = (unsigned)f2bf(f0) | ((unsigned)f2bf(f1) << 16);
  }
  uint4 o; o.x = v[0]; o.y = v[1]; o.z = v[2]; o.w = v[3];
  *reinterpret_cast<uint4*>(Bf + base + ((size_t)rel * 64 + l) * 8) = o;
}

// ---------------- gemm0 (pipelined, verified r3) ------------------------------
__global__ __launch_bounds__(256, 4) void gemm0(
    const float* __restrict__ X, const unsigned short* __restrict__ Wf,
    unsigned short* __restrict__ cur0) {
  const int ttile = blockIdx.x;
  const int b = blockIdx.y;
  const int tid = threadIdx.x;
  const int wave = tid >> 6, lane = tid & 63;
  const int t0 = ttile * 64;
  __shared__ unsigned short Xs[2][64 * 40];
  f32x4 acc[4][4];
#pragma unroll
  for (int i = 0; i < 4; ++i)
#pragma unroll
    for (int jj = 0; jj < 4; ++jj) acc[i][jj] = (f32x4)0.0f;

  const float* Xb = X + (size_t)b * NIN * TT;
  const int tt = tid & 63;
  const int kb = wave * 2;
  const int lrow = lane & 15, lgrp = lane >> 4;
  const int tgl = t0 + tt;
  const bool tin = tgl < TT;

  float r[8];
#pragma unroll
  for (int pp = 0; pp < 4; ++pp) {
    const int k = kb + pp * 8;
    r[pp * 2]     = tin ? Xb[(size_t)k * TT + tgl] : 0.0f;
    r[pp * 2 + 1] = tin ? Xb[(size_t)(k + 1) * TT + tgl] : 0.0f;
  }

  for (int kc = 0; kc < KCH0; ++kc) {
    unsigned short* xbuf = Xs[kc & 1];
#pragma unroll
    for (int pp = 0; pp < 4; ++pp) {
      const unsigned pk = (unsigned)f2bf(r[pp * 2]) | ((unsigned)f2bf(r[pp * 2 + 1]) << 16);
      *reinterpret_cast<unsigned*>(&xbuf[tt * 40 + kb + pp * 8]) = pk;
    }
    __syncthreads();
    if (kc + 1 < KCH0) {
      const int k0 = (kc + 1) * 32;
#pragma unroll
      for (int pp = 0; pp < 4; ++pp) {
        const int k = k0 + kb + pp * 8;
        r[pp * 2]     = (tin && k < NIN)     ? Xb[(size_t)k * TT + tgl] : 0.0f;
        r[pp * 2 + 1] = (tin && k + 1 < NIN) ? Xb[(size_t)(k + 1) * TT + tgl] : 0.0f;
      }
    }
    short8v afr[4], bfr[4];
#pragma unroll
    for (int jf = 0; jf < 4; ++jf) {
      const size_t off = ((size_t)((wave * 4 + jf) * KCH0 + kc) * 64 + lane) * 8;
      afr[jf] = *reinterpret_cast<const short8v*>(Wf + off);
    }
#pragma unroll
    for (int tf = 0; tf < 4; ++tf)
      bfr[tf] = *reinterpret_cast<const short8v*>(&xbuf[(tf * 16 + lrow) * 40 + lgrp * 8]);
#pragma unroll
    for (int jf = 0; jf < 4; ++jf)
#pragma unroll
      for (int tf = 0; tf < 4; ++tf)
        acc[jf][tf] = __builtin_amdgcn_mfma_f32_16x16x32_bf16(afr[jf], bfr[tf], acc[jf][tf], 0, 0, 0);
  }

#pragma unroll
  for (int tf = 0; tf < 4; ++tf) {
    const int t = t0 + tf * 16 + lrow;
    if (t >= TT) continue;
    unsigned short* row = cur0 + ((size_t)b * TT + t) * H0;
#pragma unroll
    for (int jf = 0; jf < 4; ++jf) {
      const int j = wave * 64 + jf * 16 + lgrp * 4;
      const f32x4 a = acc[jf][tf];
      const unsigned p0 = (unsigned)f2bf(a[0]) | ((unsigned)f2bf(a[1]) << 16);
      const unsigned p1 = (unsigned)f2bf(a[2]) | ((unsigned)f2bf(a[3]) << 16);
      *reinterpret_cast<unsigned*>(row + j) = p0;
      *reinterpret_cast<unsigned*>(row + j + 2) = p1;
    }
  }
}

// ---------------- LIF step helpers --------------------------------------------
template<int N>
__device__ __forceinline__ void lif_reg(float& v, const float* cr,
                                        unsigned short* sd, float* hp) {
  float hb[16];
#pragma unroll
  for (int u = 0; u < N; ++u) {
    v = 0.5f * (v + cr[u]);
    const float s = sigm5(v);
    v *= (1.0f - s);
    hb[u] = s;
    sd[(size_t)u * SW0] = f2bf(s);
  }
#pragma unroll
  for (int q = 0; q < N / 4; ++q)
    *reinterpret_cast<float4*>(hp + q * 4) =
        make_float4(hb[q * 4], hb[q * 4 + 1], hb[q * 4 + 2], hb[q * 4 + 3]);
}

template<int N>
__device__ __forceinline__ void lif_dyn(float& v, float& rate, const float* cur, int cw,
                                        unsigned short* sd, int sw, float* hp, bool wsf) {
  float hb[16];
  const float* cp = cur;
  unsigned short* sp = sd;
#pragma unroll
  for (int u = 0; u < N; ++u) {
    v = 0.5f * (v + *cp); cp += cw;
    const float s = sigm5(v);
    v *= (1.0f - s);
    hb[u] = s;
    if (wsf) *sp = f2bf(s);
    sp += sw;
    rate += s;
  }
#pragma unroll
  for (int q = 0; q < N / 4; ++q)
    *reinterpret_cast<float4*>(hp + q * 4) =
        make_float4(hb[q * 4], hb[q * 4 + 1], hb[q * 4 + 2], hb[q * 4 + 3]);
}

// ---------------- snn_tail: fused scan0+gemm1..4+scan1..4+rates ---------------
// 1 block per b, 512 thr = 8 waves. Layer-skewed pipeline over 8 chunks of 64
// steps (last = 52). Phase p: scans {l0@p, l1@p-1, l2@p-2, l3@p-3, l4@p-4} on
// disjoint thread groups; then gemm phase (all waves) computes {cur1@p,
// cur2@p-1, cur3@p-2, cur4@p-3} from LDS spike buffers. s-buffer slot u+1 holds
// spike of local step u; slot 0 = previous chunk boundary (copied at scan start).
__global__ __launch_bounds__(512, 1) void snn_tail(
    const unsigned short* __restrict__ cur0, const unsigned short* __restrict__ Bf,
    float* __restrict__ out) {
  __shared__ __align__(16) unsigned short s0b[65 * SW0];
  __shared__ __align__(16) unsigned short s1b[65 * SW1];
  __shared__ __align__(16) unsigned short s2b[65 * SW2];
  __shared__ __align__(16) unsigned short s3b[65 * SW3];
  __shared__ __align__(16) float c1b[64 * CW1];
  __shared__ __align__(16) float c2b[64 * CW2];
  __shared__ __align__(16) float c3b[64 * CW3];
  __shared__ __align__(16) float c4b[64 * CW4];

  const int b = blockIdx.x, tid = threadIdx.x;
  const int w = tid >> 6, lane = tid & 63, lr = lane & 15, lg = lane >> 4;
  const unsigned short* BfW1 = Bf;
  const unsigned short* BfW2 = Bf + 64 * 512;
  const unsigned short* BfW3 = Bf + 80 * 512;
  const unsigned short* BfW4 = Bf + 84 * 512;

  float v = 0.0f, rate = 0.0f;
  // scan-role setup for tid >= 256 (layers 1..4)
  int lay = 0, j = tid;
  const float* curb = nullptr;
  unsigned short* sb = s3b;
  float* hbase = nullptr;
  int cw = 0, sw = 0;
  bool wsf = false, sact = false;
  if (tid < 256) {
    sact = true;
    hbase = out + ((size_t)b * H0 + tid) * TT;
  } else if (tid < 384) {
    lay = 1; j = tid - 256; curb = c1b + j; sb = s1b; cw = CW1; sw = SW1; wsf = true;
    sact = true; hbase = out + H1_OFF + ((size_t)b * H1 + j) * TT;
  } else if (tid < 448) {
    lay = 2; j = tid - 384; curb = c2b + j; sb = s2b; cw = CW2; sw = SW2; wsf = true;
    sact = true; hbase = out + H2_OFF + ((size_t)b * H2 + j) * TT;
  } else if (tid < 480) {
    lay = 3; j = tid - 448; curb = c3b + j; sb = s3b; cw = CW3; sw = SW3; wsf = true;
    sact = true; hbase = out + H3_OFF + ((size_t)b * H3 + j) * TT;
  } else if (tid < 496) {
    lay = 4; j = tid - 480; curb = c4b + j; sb = s3b; cw = CW4; sw = 0; wsf = false;
    sact = (j < NOUT); hbase = out + OUT_OFF + ((size_t)b * NOUT + j) * TT;
  }
  const unsigned short* cp0 = cur0 + (size_t)b * TT * H0 + tid;

  for (int p = 0; p < 12; ++p) {
    // ================= scan phase =================
    if (tid < 256) {
      if (p <= 7) {
        const int c = p;
        s0b[tid] = (c == 0) ? (unsigned short)0 : s0b[64 * SW0 + tid];
        const unsigned short* cp = cp0 + (size_t)c * 64 * H0;
        float* hp = hbase + c * 64;
        unsigned short* sdj = s0b + tid;
        float A[16], Bv[16];
#define LD16(D, O) _Pragma("unroll") for (int u = 0; u < 16; ++u) (D)[u] = bf2f(cp[(size_t)((O) + u) * H0]);
#define LD4(D, O)  _Pragma("unroll") for (int u = 0; u < 4;  ++u) (D)[u] = bf2f(cp[(size_t)((O) + u) * H0]);
        if (c < 7) {
          LD16(A, 0); LD16(Bv, 16);
          lif_reg<16>(v, A, sdj + 1 * SW0, hp);
          LD16(A, 32);
          lif_reg<16>(v, Bv, sdj + 17 * SW0, hp + 16);
          LD16(Bv, 48);
          lif_reg<16>(v, A, sdj + 33 * SW0, hp + 32);
          lif_reg<16>(v, Bv, sdj + 49 * SW0, hp + 48);
        } else {
          LD16(A, 0); LD16(Bv, 16);
          lif_reg<16>(v, A, sdj + 1 * SW0, hp);
          LD16(A, 32);
          lif_reg<16>(v, Bv, sdj + 17 * SW0, hp + 16);
          LD4(Bv, 48);
          lif_reg<16>(v, A, sdj + 33 * SW0, hp + 32);
          lif_reg<4>(v, Bv, sdj + 49 * SW0, hp + 48);
        }
#undef LD16
#undef LD4
      }
    } else if (sact) {
      const int c = p - lay;
      if (c >= 0 && c <= 7) {
        if (wsf) sb[j] = (c == 0) ? (unsigned short)0 : sb[64 * sw + j];
        float* hp = hbase + c * 64;
        unsigned short* sbj = sb + j;
        if (c < 7) {
#pragma unroll
          for (int q = 0; q < 4; ++q)
            lif_dyn<16>(v, rate, curb + q * 16 * cw, cw, sbj + (q * 16 + 1) * sw, sw,
                        hp + q * 16, wsf);
        } else {
          lif_dyn<16>(v, rate, curb, cw, sbj + 1 * sw, sw, hp, wsf);
          lif_dyn<16>(v, rate, curb + 16 * cw, cw, sbj + 17 * sw, sw, hp + 16, wsf);
          lif_dyn<16>(v, rate, curb + 32 * cw, cw, sbj + 33 * sw, sw, hp + 32, wsf);
          lif_dyn<4>(v, rate, curb + 48 * cw, cw, sbj + 49 * sw, sw, hp + 48, wsf);
        }
      }
    }
    __syncthreads();
    // ================= gemm phase =================
    if (p <= 7) {  // gemm1: s0 chunk p -> cur1
      const int tt = w >> 1, nb = (w & 1) * 4;
      short8v a[8];
      const unsigned short* ap = s0b + (tt * 16 + lr) * SW0 + lg * 8;
#pragma unroll
      for (int kc = 0; kc < 8; ++kc) a[kc] = *reinterpret_cast<const short8v*>(ap + kc * 32);
#pragma unroll
      for (int n4 = 0; n4 < 4; ++n4) {
        const int nt = nb + n4;
        f32x4 acc = (f32x4)0.0f;
#pragma unroll
        for (int kc = 0; kc < 8; ++kc) {
          const short8v bf = *reinterpret_cast<const short8v*>(BfW1 + ((size_t)(nt * 8 + kc) * 64 + lane) * 8);
          acc = __builtin_amdgcn_mfma_f32_16x16x32_bf16(a[kc], bf, acc, 0, 0, 0);
        }
        float* cd = c1b + (tt * 16 + lg * 4) * CW1 + nt * 16 + lr;
#pragma unroll
        for (int r = 0; r < 4; ++r) cd[r * CW1] = acc[r];
      }
    }
    if (p >= 1 && p <= 8) {  // gemm2
      const int tt = w >> 1;
      short8v a[4];
      const unsigned short* ap = s1b + (tt * 16 + lr) * SW1 + lg * 8;
#pragma unroll
      for (int kc = 0; kc < 4; ++kc) a[kc] = *reinterpret_cast<const short8v*>(ap + kc * 32);
#pragma unroll
      for (int qi = 0; qi < 2; ++qi) {
        const int nt = (w & 1) * 2 + qi;
        f32x4 acc = (f32x4)0.0f;
#pragma unroll
        for (int kc = 0; kc < 4; ++kc) {
          const short8v bf = *reinterpret_cast<const short8v*>(BfW2 + ((size_t)(nt * 4 + kc) * 64 + lane) * 8);
          acc = __builtin_amdgcn_mfma_f32_16x16x32_bf16(a[kc], bf, acc, 0, 0, 0);
        }
        float* cd = c2b + (tt * 16 + lg * 4) * CW2 + nt * 16 + lr;
#pragma unroll
        for (int r = 0; r < 4; ++r) cd[r * CW2] = acc[r];
      }
    }
    if (p >= 2 && p <= 9) {  // gemm3
      const int tt = w >> 1, nt = w & 1;
      short8v a[2];
      const unsigned short* ap = s2b + (tt * 16 + lr) * SW2 + lg * 8;
#pragma unroll
      for (int kc = 0; kc < 2; ++kc) a[kc] = *reinterpret_cast<const short8v*>(ap + kc * 32);
      f32x4 acc = (f32x4)0.0f;
#pragma unroll
      for (int kc = 0; kc < 2; ++kc) {
        const short8v bf = *reinterpret_cast<const short8v*>(BfW3 + ((size_t)(nt * 2 + kc) * 64 + lane) * 8);
        acc = __builtin_amdgcn_mfma_f32_16x16x32_bf16(a[kc], bf, acc, 0, 0, 0);
      }
      float* cd = c3b + (tt * 16 + lg * 4) * CW3 + nt * 16 + lr;
#pragma unroll
      for (int r = 0; r < 4; ++r) cd[r * CW3] = acc[r];
    }
    if (p >= 3 && p <= 10 && w < 4) {  // gemm4
      const int tt = w;
      const unsigned short* ap = s3b + (tt * 16 + lr) * SW3 + lg * 8;
      const short8v a0 = *reinterpret_cast<const short8v*>(ap);
      const short8v bf = *reinterpret_cast<const short8v*>(BfW4 + (size_t)lane * 8);
      f32x4 acc = (f32x4)0.0f;
      acc = __builtin_amdgcn_mfma_f32_16x16x32_bf16(a0, bf, acc, 0, 0, 0);
      float* cd = c4b + (tt * 16 + lg * 4) * CW4 + lr;
#pragma unroll
      for (int r = 0; r < 4; ++r) cd[r * CW4] = acc[r];
    }
    __syncthreads();
  }
  if (tid >= 480 && tid < 480 + NOUT)
    out[RATE_OFF + (size_t)b * NOUT + (tid - 480)] = rate * (1.0f / (float)TT);
}

extern "C" void kernel_launch(void* const* d_in, const int* in_sizes, int n_in,
                              void* d_out, int out_size, void* d_ws, size_t ws_size,
                              hipStream_t stream) {
  const float* X  = (const float*)d_in[0];
  const float* w0 = (const float*)d_in[1];
  const float* w1 = (const float*)d_in[2];
  const float* w2 = (const float*)d_in[3];
  const float* w3 = (const float*)d_in[4];
  const float* w4 = (const float*)d_in[5];
  float* out = (float*)d_out;

  uint8_t* ws = (uint8_t*)d_ws;
  const size_t SLOT = 33554432;
  unsigned short* cur0 = (unsigned short*)ws;                 // [b][TT][256] bf16
  unsigned short* Wf0 = (unsigned short*)(ws + SLOT);         // w0 A-frags
  unsigned short* Bf2 = Wf0 + (size_t)JTILES * KCH0 * 64 * 8; // w1..w4 B-frags

  pack_all<<<JTILES * KCH0 + 85, 64, 0, stream>>>(w0, w1, w2, w3, w4, Wf0, Bf2);
  gemm0<<<dim3(8, BATCH), 256, 0, stream>>>(X, Wf0, cur0);
  snn_tail<<<BATCH, 512, 0, stream>>>(cur0, Bf2, out);
}